// Round 1
// baseline (516.398 us; speedup 1.0000x reference)
//
#include <hip/hip_runtime.h>
#include <hip/hip_bf16.h>

typedef unsigned short u16;
typedef __bf16 bf16x8 __attribute__((ext_vector_type(8)));
typedef float f32x4 __attribute__((ext_vector_type(4)));

#define AS1 __attribute__((address_space(1)))
#define AS3 __attribute__((address_space(3)))
#define GLL16(gp, lp) __builtin_amdgcn_global_load_lds((AS1 const unsigned int*)(gp), (AS3 unsigned int*)(lp), 16, 0, 0)

__device__ __forceinline__ u16 f2bf(float f) {
    unsigned u = __builtin_bit_cast(unsigned, f);
    unsigned r = u + 0x7FFFu + ((u >> 16) & 1u);
    return (u16)(r >> 16);
}

// ---------------- mask dtype detector ----------------
// flag: 0=u8(bool), 1=i32, 2=f32, 3=bf16
__global__ void detect_kernel(const unsigned char* __restrict__ m, int* __restrict__ flag) {
    __shared__ int cnt1;   // nonzero bytes at pos%4==1
    __shared__ int big;    // bytes with value > 1
    if (threadIdx.x == 0) { cnt1 = 0; big = 0; }
    __syncthreads();
    int c1 = 0, bg = 0;
    for (int i = threadIdx.x; i < 16384; i += 256) {
        unsigned char v = m[i];
        if (v) {
            if ((i & 3) == 1) c1++;
            if (v > 1) bg++;
        }
    }
    atomicAdd(&cnt1, c1);
    atomicAdd(&big, bg);
    __syncthreads();
    if (threadIdx.x == 0) {
        int f;
        if (big == 0) f = cnt1 ? 0 : 1;   // u8 bool vs int32
        else          f = cnt1 ? 3 : 2;   // bf16 vs f32
        *flag = f;
    }
}

// ---------------- f32 -> bf16 cast of Q/K/V inputs ----------------
__global__ void cast3_kernel(const float* __restrict__ q, const float* __restrict__ k,
                             const float* __restrict__ v, u16* __restrict__ xq,
                             u16* __restrict__ xk, u16* __restrict__ xv) {
    const int n4 = 4 * 1024 * 1024 / 4;
    int stride = gridDim.x * blockDim.x;
    for (int i = blockIdx.x * blockDim.x + threadIdx.x; i < n4; i += stride) {
        float4 a = ((const float4*)q)[i];
        float4 b = ((const float4*)k)[i];
        float4 c = ((const float4*)v)[i];
        ((ushort4*)xq)[i] = make_ushort4(f2bf(a.x), f2bf(a.y), f2bf(a.z), f2bf(a.w));
        ((ushort4*)xk)[i] = make_ushort4(f2bf(b.x), f2bf(b.y), f2bf(b.z), f2bf(b.w));
        ((ushort4*)xv)[i] = make_ushort4(f2bf(c.x), f2bf(c.y), f2bf(c.z), f2bf(c.w));
    }
}

// ---------------- weight transpose + cast: W[k][n] f32 -> Wt[n][k] bf16 ----------------
__global__ __launch_bounds__(256) void wtrans_kernel(
    const float* __restrict__ W0, const float* __restrict__ W1,
    const float* __restrict__ W2, const float* __restrict__ W3,
    u16* __restrict__ T0, u16* __restrict__ T1, u16* __restrict__ T2, u16* __restrict__ T3) {
    const float* W = (blockIdx.z == 0) ? W0 : (blockIdx.z == 1) ? W1 : (blockIdx.z == 2) ? W2 : W3;
    u16* T = (blockIdx.z == 0) ? T0 : (blockIdx.z == 1) ? T1 : (blockIdx.z == 2) ? T2 : T3;
    __shared__ float t[64][65];
    const int n0 = blockIdx.x * 64, k0 = blockIdx.y * 64;
    const int tx = threadIdx.x, ty = threadIdx.y;
    for (int j = ty; j < 64; j += 4) t[j][tx] = W[(size_t)(k0 + j) * 1024 + n0 + tx];
    __syncthreads();
    for (int j = ty; j < 64; j += 4) T[(size_t)(n0 + j) * 1024 + k0 + tx] = f2bf(t[tx][j]);
}

// ---------------- GEMM: C = A(M,K) @ Bt(N,K)^T + bias, bf16 MFMA ----------------
// MODE 0: out bf16 row-major, scaled.  MODE 1: out bf16 per-head-transposed (V^T).
// MODE 2: out f32 = acc + bias + resid.
template <int MODE>
__global__ __launch_bounds__(256) void gemm_bt(
    const u16* __restrict__ A, const u16* __restrict__ Bt, const float* __restrict__ bias,
    void* __restrict__ outp, const float* __restrict__ resid, int M, int N, int K, float scale) {
    __shared__ __align__(16) u16 lsA[128 * 64];
    __shared__ __align__(16) u16 lsB[128 * 64];
    const int tid = threadIdx.x, lane = tid & 63, wid = tid >> 6;
    const int bm = blockIdx.y, bn = blockIdx.x;
    const int wr = wid >> 1, wc = wid & 1;
    const int l15 = lane & 15, l4 = lane >> 4;
    f32x4 acc[4][4] = {};
    const int cbase = wid * 256;  // 4 chunks-of-64 per wave
    const int nt = K >> 6;
    for (int t = 0; t < nt; ++t) {
        __syncthreads();
        for (int j = 0; j < 4; ++j) {
            int c = cbase + j * 64 + lane;
            int row = c >> 3, off = (c & 7) * 8;
            const u16* ga = A + (size_t)(bm * 128 + row) * K + t * 64 + off;
            GLL16(ga, lsA + (size_t)(cbase + j * 64) * 8);
            const u16* gb = Bt + (size_t)(bn * 128 + row) * K + t * 64 + off;
            GLL16(gb, lsB + (size_t)(cbase + j * 64) * 8);
        }
        __syncthreads();
        for (int kk = 0; kk < 2; ++kk) {
            bf16x8 af[4], bfr[4];
            for (int m = 0; m < 4; ++m)
                af[m] = *(const bf16x8*)(lsA + (wr * 64 + m * 16 + l15) * 64 + kk * 32 + l4 * 8);
            for (int n = 0; n < 4; ++n)
                bfr[n] = *(const bf16x8*)(lsB + (wc * 64 + n * 16 + l15) * 64 + kk * 32 + l4 * 8);
            for (int m = 0; m < 4; ++m)
                for (int n = 0; n < 4; ++n)
                    acc[m][n] = __builtin_amdgcn_mfma_f32_16x16x32_bf16(af[m], bfr[n], acc[m][n], 0, 0, 0);
        }
    }
    for (int n = 0; n < 4; ++n) {
        int c = bn * 128 + wc * 64 + n * 16 + l15;
        float bv = bias[c];
        for (int m = 0; m < 4; ++m) {
            for (int j = 0; j < 4; ++j) {
                int r = bm * 128 + wr * 64 + m * 16 + l4 * 4 + j;
                float v = acc[m][n][j];
                if (MODE == 0) {
                    ((u16*)outp)[(size_t)r * N + c] = f2bf((v + bv) * scale);
                } else if (MODE == 1) {
                    int bb = r >> 10, k = r & 1023, h = c >> 6, d = c & 63;
                    ((u16*)outp)[((size_t)((bb * 16 + h) * 64 + d)) * 1024 + k] = f2bf(v + bv);
                } else {
                    ((float*)outp)[(size_t)r * N + c] = v + bv + resid[(size_t)r * N + c];
                }
            }
        }
    }
}

// ---------------- fused geometry attention ----------------
// Qs: (B*NQ, H*64) bf16 pre-scaled by 1/8.  Ks: (B*NK, H*64) bf16.
// Vt: (B*H*64, NK) bf16.  geom: (B,H,NQ,NK) f32.  AO: (B*NQ, H*64) bf16.
__global__ __launch_bounds__(256) void attn_kernel(
    const u16* __restrict__ Qs, const u16* __restrict__ Ks, const u16* __restrict__ Vt,
    const float* __restrict__ geom, const void* __restrict__ maskp,
    const int* __restrict__ flagp, u16* __restrict__ AO) {
    __shared__ __align__(16) u16 pbuf[4][16][72];
    const int b = blockIdx.z, h = blockIdx.y, q0 = blockIdx.x * 64;
    const int tid = threadIdx.x, lane = tid & 63, wid = tid >> 6;
    const int l15 = lane & 15, l4 = lane >> 4;
    const int flag = *flagp;
    const int qrow = q0 + wid * 16;
    const size_t bh = (size_t)(b * 16 + h);

    const u16* qp = Qs + (size_t)(b * 1024 + qrow + l15) * 1024 + h * 64 + l4 * 8;
    bf16x8 aq0 = *(const bf16x8*)qp;
    bf16x8 aq1 = *(const bf16x8*)(qp + 32);

    f32x4 o[4] = {};
    float m_run[4], l_run[4];
    for (int j = 0; j < 4; ++j) { m_run[j] = -1e30f; l_run[j] = 0.f; }

    const unsigned char* m8 = (const unsigned char*)maskp;
    const int* m32 = (const int*)maskp;
    const float* mf = (const float*)maskp;
    const u16* mb = (const u16*)maskp;

    for (int kb = 0; kb < 16; ++kb) {
        f32x4 s[4];
        for (int nf = 0; nf < 4; ++nf) {
            const u16* kp = Ks + (size_t)(b * 1024 + kb * 64 + nf * 16 + l15) * 1024 + h * 64 + l4 * 8;
            bf16x8 k0 = *(const bf16x8*)kp;
            bf16x8 k1 = *(const bf16x8*)(kp + 32);
            f32x4 z = {};
            z = __builtin_amdgcn_mfma_f32_16x16x32_bf16(aq0, k0, z, 0, 0, 0);
            s[nf] = __builtin_amdgcn_mfma_f32_16x16x32_bf16(aq1, k1, z, 0, 0, 0);
        }
        // geometry log-bias + mask
        for (int j = 0; j < 4; ++j) {
            size_t gbase = (bh * 1024 + (qrow + l4 * 4 + j)) * 1024 + kb * 64 + l15;
            for (int nf = 0; nf < 4; ++nf) {
                size_t gi = gbase + nf * 16;
                bool msk;
                if (flag == 0)      msk = m8[gi] != 0;
                else if (flag == 1) msk = m32[gi] != 0;
                else if (flag == 2) msk = mf[gi] != 0.f;
                else                msk = mb[gi] != 0;
                float gv = geom[gi];
                s[nf][j] = msk ? -1e30f : (s[nf][j] + __logf(fmaxf(gv, 1e-6f)));
            }
        }
        // online softmax (row-groups of 16 lanes)
        float scl[4];
        for (int j = 0; j < 4; ++j) {
            float mt = fmaxf(fmaxf(s[0][j], s[1][j]), fmaxf(s[2][j], s[3][j]));
            for (int d = 1; d < 16; d <<= 1) mt = fmaxf(mt, __shfl_xor(mt, d, 16));
            float mn = fmaxf(m_run[j], mt);
            scl[j] = __expf(m_run[j] - mn);
            float rs = 0.f;
            for (int nf = 0; nf < 4; ++nf) {
                float p = __expf(s[nf][j] - mn);
                s[nf][j] = p;
                rs += p;
            }
            for (int d = 1; d < 16; d <<= 1) rs += __shfl_xor(rs, d, 16);
            l_run[j] = l_run[j] * scl[j] + rs;
            m_run[j] = mn;
        }
        for (int df = 0; df < 4; ++df) {
            f32x4 t = o[df];
            for (int j = 0; j < 4; ++j) t[j] *= scl[j];
            o[df] = t;
        }
        // P -> LDS (C-layout) then read back as A-fragments
        __syncthreads();
        for (int nf = 0; nf < 4; ++nf)
            for (int j = 0; j < 4; ++j)
                pbuf[wid][l4 * 4 + j][nf * 16 + l15] = f2bf(s[nf][j]);
        __syncthreads();
        bf16x8 pa0 = *(const bf16x8*)&pbuf[wid][l15][l4 * 8];
        bf16x8 pa1 = *(const bf16x8*)&pbuf[wid][l15][32 + l4 * 8];
        for (int df = 0; df < 4; ++df) {
            const u16* vp = Vt + (bh * 64 + df * 16 + l15) * 1024 + kb * 64 + l4 * 8;
            bf16x8 v0 = *(const bf16x8*)vp;
            bf16x8 v1 = *(const bf16x8*)(vp + 32);
            o[df] = __builtin_amdgcn_mfma_f32_16x16x32_bf16(pa0, v0, o[df], 0, 0, 0);
            o[df] = __builtin_amdgcn_mfma_f32_16x16x32_bf16(pa1, v1, o[df], 0, 0, 0);
        }
    }
    for (int df = 0; df < 4; ++df)
        for (int j = 0; j < 4; ++j) {
            int r = b * 1024 + qrow + l4 * 4 + j;
            int c = h * 64 + df * 16 + l15;
            AO[(size_t)r * 1024 + c] = f2bf(o[df][j] / l_run[j]);
        }
}

// ---------------- LayerNorm over rows of Y (f32) ----------------
__global__ __launch_bounds__(256) void ln_kernel(const float* __restrict__ Y,
                                                 const float* __restrict__ gamma,
                                                 const float* __restrict__ beta,
                                                 float* __restrict__ out) {
    __shared__ float red[8];
    const int r = blockIdx.x, tid = threadIdx.x, lane = tid & 63, wid = tid >> 6;
    float4 v = ((const float4*)(Y + (size_t)r * 1024))[tid];
    float s = v.x + v.y + v.z + v.w;
    float q = v.x * v.x + v.y * v.y + v.z * v.z + v.w * v.w;
    for (int d = 1; d < 64; d <<= 1) {
        s += __shfl_xor(s, d, 64);
        q += __shfl_xor(q, d, 64);
    }
    if (lane == 0) { red[wid] = s; red[4 + wid] = q; }
    __syncthreads();
    float ts = red[0] + red[1] + red[2] + red[3];
    float tq = red[4] + red[5] + red[6] + red[7];
    float mu = ts * (1.f / 1024.f);
    float var = tq * (1.f / 1024.f) - mu * mu;
    float rstd = rsqrtf(var + 1e-5f);
    float4 g = ((const float4*)gamma)[tid];
    float4 be = ((const float4*)beta)[tid];
    float4 ov;
    ov.x = (v.x - mu) * rstd * g.x + be.x;
    ov.y = (v.y - mu) * rstd * g.y + be.y;
    ov.z = (v.z - mu) * rstd * g.z + be.z;
    ov.w = (v.w - mu) * rstd * g.w + be.w;
    ((float4*)(out + (size_t)r * 1024))[tid] = ov;
}

extern "C" void kernel_launch(void* const* d_in, const int* in_sizes, int n_in,
                              void* d_out, int out_size, void* d_ws, size_t ws_size,
                              hipStream_t stream) {
    const float* queries = (const float*)d_in[0];
    const float* keys    = (const float*)d_in[1];
    const float* values  = (const float*)d_in[2];
    const float* geom    = (const float*)d_in[3];
    const void*  mask    = d_in[4];
    const float* Wq = (const float*)d_in[5];  const float* bq = (const float*)d_in[6];
    const float* Wk = (const float*)d_in[7];  const float* bk = (const float*)d_in[8];
    const float* Wv = (const float*)d_in[9];  const float* bv = (const float*)d_in[10];
    const float* Wo = (const float*)d_in[11]; const float* bo = (const float*)d_in[12];
    const float* gamma = (const float*)d_in[13];
    const float* beta  = (const float*)d_in[14];

    char* ws = (char*)d_ws;
    const size_t MB = 1024 * 1024;
    u16* XQ  = (u16*)(ws + 0);
    u16* XK  = (u16*)(ws + 8 * MB);
    u16* XV  = (u16*)(ws + 16 * MB);
    u16* WQT = (u16*)(ws + 24 * MB);
    u16* WKT = (u16*)(ws + 26 * MB);
    u16* WVT = (u16*)(ws + 28 * MB);
    u16* WOT = (u16*)(ws + 30 * MB);
    u16* QS  = (u16*)(ws + 32 * MB);
    u16* KS  = (u16*)(ws + 40 * MB);
    u16* VT  = (u16*)(ws + 48 * MB);
    u16* AO  = (u16*)(ws + 56 * MB);
    float* Y = (float*)(ws + 0);        // reuses XQ/XK region (dead by then)
    int* FLAG = (int*)(ws + 64 * MB);

    detect_kernel<<<1, 256, 0, stream>>>((const unsigned char*)mask, FLAG);
    cast3_kernel<<<1024, 256, 0, stream>>>(queries, keys, values, XQ, XK, XV);
    wtrans_kernel<<<dim3(16, 16, 4), dim3(64, 4), 0, stream>>>(Wq, Wk, Wv, Wo, WQT, WKT, WVT, WOT);
    gemm_bt<0><<<dim3(8, 32), 256, 0, stream>>>(XQ, WQT, bq, QS, nullptr, 4096, 1024, 1024, 0.125f);
    gemm_bt<0><<<dim3(8, 32), 256, 0, stream>>>(XK, WKT, bk, KS, nullptr, 4096, 1024, 1024, 1.0f);
    gemm_bt<1><<<dim3(8, 32), 256, 0, stream>>>(XV, WVT, bv, VT, nullptr, 4096, 1024, 1024, 1.0f);
    attn_kernel<<<dim3(16, 16, 4), 256, 0, stream>>>(QS, KS, VT, geom, mask, FLAG, AO);
    gemm_bt<2><<<dim3(8, 32), 256, 0, stream>>>(AO, WOT, bo, Y, queries, 4096, 1024, 1024, 1.0f);
    ln_kernel<<<4096, 256, 0, stream>>>(Y, gamma, beta, (float*)d_out);
}

// Round 2
// 430.834 us; speedup vs baseline: 1.1986x; 1.1986x over previous
//
#include <hip/hip_runtime.h>
#include <hip/hip_bf16.h>

typedef unsigned short u16;
typedef __bf16 bf16x8 __attribute__((ext_vector_type(8)));
typedef float f32x4 __attribute__((ext_vector_type(4)));

#define AS1 __attribute__((address_space(1)))
#define AS3 __attribute__((address_space(3)))
#define GLL16(gp, lp) __builtin_amdgcn_global_load_lds((AS1 const unsigned int*)(gp), (AS3 unsigned int*)(lp), 16, 0, 0)

__device__ __forceinline__ u16 f2bf(float f) {
    unsigned u = __builtin_bit_cast(unsigned, f);
    unsigned r = u + 0x7FFFu + ((u >> 16) & 1u);
    return (u16)(r >> 16);
}

// ---------------- mask dtype detector ----------------
// flag: 0=u8(bool), 1=i32, 2=f32, 3=bf16
__global__ void detect_kernel(const unsigned char* __restrict__ m, int* __restrict__ flag) {
    __shared__ int cnt1;   // nonzero bytes at pos%4==1
    __shared__ int big;    // bytes with value > 1
    if (threadIdx.x == 0) { cnt1 = 0; big = 0; }
    __syncthreads();
    int c1 = 0, bg = 0;
    for (int i = threadIdx.x; i < 16384; i += 256) {
        unsigned char v = m[i];
        if (v) {
            if ((i & 3) == 1) c1++;
            if (v > 1) bg++;
        }
    }
    atomicAdd(&cnt1, c1);
    atomicAdd(&big, bg);
    __syncthreads();
    if (threadIdx.x == 0) {
        int f;
        if (big == 0) f = cnt1 ? 0 : 1;   // u8 bool vs int32
        else          f = cnt1 ? 3 : 2;   // bf16 vs f32
        *flag = f;
    }
}

// ---------------- mask -> packed bitmask (64M elements -> 8MB u64 words) ----------------
// MB word index = row*16 + kb, bit L = mask[row*1024 + kb*64 + L] nonzero.
#define MN_LOOP(PRED)                                                     \
    for (int row = wave; row < 65536; row += nw) {                        \
        size_t base = (size_t)row * 1024;                                 \
        unsigned long long myw = 0;                                       \
        _Pragma("unroll")                                                 \
        for (int kb = 0; kb < 16; ++kb) {                                 \
            size_t gi = base + kb * 64 + lane;                            \
            bool p = (PRED);                                              \
            unsigned long long w = __ballot(p);                           \
            if (lane == kb) myw = w;                                      \
        }                                                                 \
        if (lane < 16) MB[(size_t)row * 16 + lane] = myw;                 \
    }

__global__ __launch_bounds__(256) void masknorm_kernel(const void* __restrict__ mp,
                                                       const int* __restrict__ flagp,
                                                       unsigned long long* __restrict__ MB) {
    const int flag = *flagp;
    const int lane = threadIdx.x & 63;
    const int wave = blockIdx.x * 4 + (threadIdx.x >> 6);
    const int nw = gridDim.x * 4;
    if (flag == 0) {
        const unsigned char* m8 = (const unsigned char*)mp;
        MN_LOOP(m8[gi] != 0)
    } else if (flag == 1) {
        const int* m32 = (const int*)mp;
        MN_LOOP(m32[gi] != 0)
    } else if (flag == 2) {
        const unsigned* mf = (const unsigned*)mp;
        MN_LOOP((mf[gi] << 1) != 0)
    } else {
        const u16* mb = (const u16*)mp;
        MN_LOOP((mb[gi] & 0x7FFF) != 0)
    }
}

// ---------------- f32 -> bf16 cast of Q/K/V inputs ----------------
__global__ void cast3_kernel(const float* __restrict__ q, const float* __restrict__ k,
                             const float* __restrict__ v, u16* __restrict__ xq,
                             u16* __restrict__ xk, u16* __restrict__ xv) {
    const int n4 = 4 * 1024 * 1024 / 4;
    int stride = gridDim.x * blockDim.x;
    for (int i = blockIdx.x * blockDim.x + threadIdx.x; i < n4; i += stride) {
        float4 a = ((const float4*)q)[i];
        float4 b = ((const float4*)k)[i];
        float4 c = ((const float4*)v)[i];
        ((ushort4*)xq)[i] = make_ushort4(f2bf(a.x), f2bf(a.y), f2bf(a.z), f2bf(a.w));
        ((ushort4*)xk)[i] = make_ushort4(f2bf(b.x), f2bf(b.y), f2bf(b.z), f2bf(b.w));
        ((ushort4*)xv)[i] = make_ushort4(f2bf(c.x), f2bf(c.y), f2bf(c.z), f2bf(c.w));
    }
}

// ---------------- weight transpose + cast: W[k][n] f32 -> Wt[n][k] bf16 ----------------
__global__ __launch_bounds__(256) void wtrans_kernel(
    const float* __restrict__ W0, const float* __restrict__ W1,
    const float* __restrict__ W2, const float* __restrict__ W3,
    u16* __restrict__ T0, u16* __restrict__ T1, u16* __restrict__ T2, u16* __restrict__ T3) {
    const float* W = (blockIdx.z == 0) ? W0 : (blockIdx.z == 1) ? W1 : (blockIdx.z == 2) ? W2 : W3;
    u16* T = (blockIdx.z == 0) ? T0 : (blockIdx.z == 1) ? T1 : (blockIdx.z == 2) ? T2 : T3;
    __shared__ float t[64][65];
    const int n0 = blockIdx.x * 64, k0 = blockIdx.y * 64;
    const int tx = threadIdx.x, ty = threadIdx.y;
    for (int j = ty; j < 64; j += 4) t[j][tx] = W[(size_t)(k0 + j) * 1024 + n0 + tx];
    __syncthreads();
    for (int j = ty; j < 64; j += 4) T[(size_t)(n0 + j) * 1024 + k0 + tx] = f2bf(t[tx][j]);
}

// ---------------- GEMM: C = A(M,K) @ Bt(N,K)^T + bias, bf16 MFMA ----------------
template <int MODE>
__global__ __launch_bounds__(256) void gemm_bt(
    const u16* __restrict__ A, const u16* __restrict__ Bt, const float* __restrict__ bias,
    void* __restrict__ outp, const float* __restrict__ resid, int M, int N, int K, float scale) {
    __shared__ __align__(16) u16 lsA[128 * 64];
    __shared__ __align__(16) u16 lsB[128 * 64];
    const int tid = threadIdx.x, lane = tid & 63, wid = tid >> 6;
    const int bm = blockIdx.y, bn = blockIdx.x;
    const int wr = wid >> 1, wc = wid & 1;
    const int l15 = lane & 15, l4 = lane >> 4;
    f32x4 acc[4][4] = {};
    const int cbase = wid * 256;
    const int nt = K >> 6;
    for (int t = 0; t < nt; ++t) {
        __syncthreads();
        for (int j = 0; j < 4; ++j) {
            int c = cbase + j * 64 + lane;
            int row = c >> 3, off = (c & 7) * 8;
            const u16* ga = A + (size_t)(bm * 128 + row) * K + t * 64 + off;
            GLL16(ga, lsA + (size_t)(cbase + j * 64) * 8);
            const u16* gb = Bt + (size_t)(bn * 128 + row) * K + t * 64 + off;
            GLL16(gb, lsB + (size_t)(cbase + j * 64) * 8);
        }
        __syncthreads();
        for (int kk = 0; kk < 2; ++kk) {
            bf16x8 af[4], bfr[4];
            for (int m = 0; m < 4; ++m)
                af[m] = *(const bf16x8*)(lsA + (wr * 64 + m * 16 + l15) * 64 + kk * 32 + l4 * 8);
            for (int n = 0; n < 4; ++n)
                bfr[n] = *(const bf16x8*)(lsB + (wc * 64 + n * 16 + l15) * 64 + kk * 32 + l4 * 8);
            for (int m = 0; m < 4; ++m)
                for (int n = 0; n < 4; ++n)
                    acc[m][n] = __builtin_amdgcn_mfma_f32_16x16x32_bf16(af[m], bfr[n], acc[m][n], 0, 0, 0);
        }
    }
    for (int n = 0; n < 4; ++n) {
        int c = bn * 128 + wc * 64 + n * 16 + l15;
        float bv = bias[c];
        for (int m = 0; m < 4; ++m) {
            for (int j = 0; j < 4; ++j) {
                int r = bm * 128 + wr * 64 + m * 16 + l4 * 4 + j;
                float v = acc[m][n][j];
                if (MODE == 0) {
                    ((u16*)outp)[(size_t)r * N + c] = f2bf((v + bv) * scale);
                } else if (MODE == 1) {
                    int bb = r >> 10, k = r & 1023, h = c >> 6, d = c & 63;
                    ((u16*)outp)[((size_t)((bb * 16 + h) * 64 + d)) * 1024 + k] = f2bf(v + bv);
                } else {
                    ((float*)outp)[(size_t)r * N + c] = v + bv + resid[(size_t)r * N + c];
                }
            }
        }
    }
}

// ---------------- fused geometry attention (LDS-staged geometry + bitmask) ----------------
// Qs: (B*NQ, H*64) bf16 pre-scaled by 1/8.  Ks: (B*NK, H*64) bf16.
// Vt: (B*H*64, NK) bf16.  geom: (B,H,NQ,NK) f32.  MB: packed mask bits.
__global__ __launch_bounds__(256) void attn_kernel(
    const u16* __restrict__ Qs, const u16* __restrict__ Ks, const u16* __restrict__ Vt,
    const float* __restrict__ geom, const unsigned long long* __restrict__ MB,
    u16* __restrict__ AO) {
    __shared__ __align__(16) float gbuf[4096];            // 64 rows x 64 cols f32 (swizzled)
    __shared__ unsigned long long mw[64 * 17];            // mask words, padded stride 17
    __shared__ __align__(16) u16 pbuf[4][16][72];

    // XCD-aware decode: blocks sharing (b,h) K/V land on the same XCD
    const int g = blockIdx.x;
    const int t = (g & 7) * 128 + (g >> 3);
    const int qb = t & 15;
    const int bhid = t >> 4;              // 0..63
    const int b = bhid >> 4, h = bhid & 15;
    const int q0 = qb * 64;

    const int tid = threadIdx.x, lane = tid & 63, wid = tid >> 6;
    const int l15 = lane & 15, l4 = lane >> 4;
    const int qrow = q0 + wid * 16;
    const size_t bh = (size_t)bhid;

    const u16* qp = Qs + (size_t)(b * 1024 + qrow + l15) * 1024 + h * 64 + l4 * 8;
    bf16x8 aq0 = *(const bf16x8*)qp;
    bf16x8 aq1 = *(const bf16x8*)(qp + 32);

    // stage all mask words for this block once (64 rows x 16 words)
    for (int u = tid; u < 1024; u += 256) {
        int r = u >> 4, w = u & 15;
        mw[r * 17 + w] = MB[(bh * 1024 + q0 + r) * 16 + w];
    }

    f32x4 o[4] = {};
    float m_run[4], l_run[4];
    for (int j = 0; j < 4; ++j) { m_run[j] = -1e30f; l_run[j] = 0.f; }

    for (int kb = 0; kb < 16; ++kb) {
        __syncthreads();   // previous tile's gbuf reads done (also fences mw on kb==0)
        // stage geometry tile: 64x64 f32, source-swizzled so reads are conflict-light
#pragma unroll
        for (int it = 0; it < 4; ++it) {
            int u = it * 256 + tid;
            int row = u >> 4;
            int cu = (u & 15) ^ (((u >> 6) & 3) << 2);
            const float* src = geom + (bh * 1024 + q0 + row) * 1024 + (size_t)kb * 64 + cu * 4;
            GLL16(src, (char*)gbuf + (size_t)(it * 256 + wid * 64) * 16);
        }
        __syncthreads();   // staging drained (compiler emits vmcnt(0))

        // QK^T
        f32x4 s[4];
#pragma unroll
        for (int nf = 0; nf < 4; ++nf) {
            const u16* kp = Ks + (size_t)(b * 1024 + kb * 64 + nf * 16 + l15) * 1024 + h * 64 + l4 * 8;
            bf16x8 k0 = *(const bf16x8*)kp;
            bf16x8 k1 = *(const bf16x8*)(kp + 32);
            f32x4 z = {};
            z = __builtin_amdgcn_mfma_f32_16x16x32_bf16(aq0, k0, z, 0, 0, 0);
            s[nf] = __builtin_amdgcn_mfma_f32_16x16x32_bf16(aq1, k1, z, 0, 0, 0);
        }
        // geometry log-bias + mask from LDS
#pragma unroll
        for (int j = 0; j < 4; ++j) {
            const int r = wid * 16 + l4 * 4 + j;
            const unsigned long long mword = mw[r * 17 + kb];
#pragma unroll
            for (int nf = 0; nf < 4; ++nf) {
                bool msk = (mword >> (nf * 16 + l15)) & 1ULL;
                float gv = gbuf[r * 64 + ((nf ^ l4) << 4) + l15];
                s[nf][j] = msk ? -1e30f : (s[nf][j] + __logf(fmaxf(gv, 1e-6f)));
            }
        }
        // online softmax (row-groups of 16 lanes)
        float scl[4];
#pragma unroll
        for (int j = 0; j < 4; ++j) {
            float mt = fmaxf(fmaxf(s[0][j], s[1][j]), fmaxf(s[2][j], s[3][j]));
            for (int d = 1; d < 16; d <<= 1) mt = fmaxf(mt, __shfl_xor(mt, d, 16));
            float mn = fmaxf(m_run[j], mt);
            scl[j] = __expf(m_run[j] - mn);
            float rs = 0.f;
            for (int nf = 0; nf < 4; ++nf) {
                float p = __expf(s[nf][j] - mn);
                s[nf][j] = p;
                rs += p;
            }
            for (int d = 1; d < 16; d <<= 1) rs += __shfl_xor(rs, d, 16);
            l_run[j] = l_run[j] * scl[j] + rs;
            m_run[j] = mn;
        }
#pragma unroll
        for (int df = 0; df < 4; ++df) {
            f32x4 tt = o[df];
            for (int j = 0; j < 4; ++j) tt[j] *= scl[j];
            o[df] = tt;
        }
        // P -> LDS (wave-private buffer, no block barrier needed)
#pragma unroll
        for (int nf = 0; nf < 4; ++nf)
            for (int j = 0; j < 4; ++j)
                pbuf[wid][l4 * 4 + j][nf * 16 + l15] = f2bf(s[nf][j]);
        bf16x8 pa0 = *(const bf16x8*)&pbuf[wid][l15][l4 * 8];
        bf16x8 pa1 = *(const bf16x8*)&pbuf[wid][l15][32 + l4 * 8];
#pragma unroll
        for (int df = 0; df < 4; ++df) {
            const u16* vp = Vt + (bh * 64 + df * 16 + l15) * 1024 + (size_t)kb * 64 + l4 * 8;
            bf16x8 v0 = *(const bf16x8*)vp;
            bf16x8 v1 = *(const bf16x8*)(vp + 32);
            o[df] = __builtin_amdgcn_mfma_f32_16x16x32_bf16(pa0, v0, o[df], 0, 0, 0);
            o[df] = __builtin_amdgcn_mfma_f32_16x16x32_bf16(pa1, v1, o[df], 0, 0, 0);
        }
    }
#pragma unroll
    for (int df = 0; df < 4; ++df)
        for (int j = 0; j < 4; ++j) {
            int r = b * 1024 + qrow + l4 * 4 + j;
            int c = h * 64 + df * 16 + l15;
            AO[(size_t)r * 1024 + c] = f2bf(o[df][j] / l_run[j]);
        }
}

// ---------------- LayerNorm over rows of Y (f32) ----------------
__global__ __launch_bounds__(256) void ln_kernel(const float* __restrict__ Y,
                                                 const float* __restrict__ gamma,
                                                 const float* __restrict__ beta,
                                                 float* __restrict__ out) {
    __shared__ float red[8];
    const int r = blockIdx.x, tid = threadIdx.x, lane = tid & 63, wid = tid >> 6;
    float4 v = ((const float4*)(Y + (size_t)r * 1024))[tid];
    float s = v.x + v.y + v.z + v.w;
    float q = v.x * v.x + v.y * v.y + v.z * v.z + v.w * v.w;
    for (int d = 1; d < 64; d <<= 1) {
        s += __shfl_xor(s, d, 64);
        q += __shfl_xor(q, d, 64);
    }
    if (lane == 0) { red[wid] = s; red[4 + wid] = q; }
    __syncthreads();
    float ts = red[0] + red[1] + red[2] + red[3];
    float tq = red[4] + red[5] + red[6] + red[7];
    float mu = ts * (1.f / 1024.f);
    float var = tq * (1.f / 1024.f) - mu * mu;
    float rstd = rsqrtf(var + 1e-5f);
    float4 g = ((const float4*)gamma)[tid];
    float4 be = ((const float4*)beta)[tid];
    float4 ov;
    ov.x = (v.x - mu) * rstd * g.x + be.x;
    ov.y = (v.y - mu) * rstd * g.y + be.y;
    ov.z = (v.z - mu) * rstd * g.z + be.z;
    ov.w = (v.w - mu) * rstd * g.w + be.w;
    ((float4*)(out + (size_t)r * 1024))[tid] = ov;
}

extern "C" void kernel_launch(void* const* d_in, const int* in_sizes, int n_in,
                              void* d_out, int out_size, void* d_ws, size_t ws_size,
                              hipStream_t stream) {
    const float* queries = (const float*)d_in[0];
    const float* keys    = (const float*)d_in[1];
    const float* values  = (const float*)d_in[2];
    const float* geom    = (const float*)d_in[3];
    const void*  mask    = d_in[4];
    const float* Wq = (const float*)d_in[5];  const float* bq = (const float*)d_in[6];
    const float* Wk = (const float*)d_in[7];  const float* bk = (const float*)d_in[8];
    const float* Wv = (const float*)d_in[9];  const float* bv = (const float*)d_in[10];
    const float* Wo = (const float*)d_in[11]; const float* bo = (const float*)d_in[12];
    const float* gamma = (const float*)d_in[13];
    const float* beta  = (const float*)d_in[14];

    char* ws = (char*)d_ws;
    const size_t MB_ = 1024 * 1024;
    u16* XQ  = (u16*)(ws + 0);
    u16* XK  = (u16*)(ws + 8 * MB_);
    u16* XV  = (u16*)(ws + 16 * MB_);
    u16* WQT = (u16*)(ws + 24 * MB_);
    u16* WKT = (u16*)(ws + 26 * MB_);
    u16* WVT = (u16*)(ws + 28 * MB_);
    u16* WOT = (u16*)(ws + 30 * MB_);
    u16* QS  = (u16*)(ws + 32 * MB_);
    u16* KS  = (u16*)(ws + 40 * MB_);
    u16* VT  = (u16*)(ws + 48 * MB_);
    u16* AO  = (u16*)(ws + 56 * MB_);
    unsigned long long* MBITS = (unsigned long long*)(ws + 16 * MB_);  // reuses XV (dead after V GEMM)
    float* Y = (float*)(ws + 0);        // reuses XQ/XK region (dead by then)
    int* FLAG = (int*)(ws + 64 * MB_);

    detect_kernel<<<1, 256, 0, stream>>>((const unsigned char*)mask, FLAG);
    cast3_kernel<<<1024, 256, 0, stream>>>(queries, keys, values, XQ, XK, XV);
    wtrans_kernel<<<dim3(16, 16, 4), dim3(64, 4), 0, stream>>>(Wq, Wk, Wv, Wo, WQT, WKT, WVT, WOT);
    gemm_bt<0><<<dim3(8, 32), 256, 0, stream>>>(XQ, WQT, bq, QS, nullptr, 4096, 1024, 1024, 0.125f);
    gemm_bt<0><<<dim3(8, 32), 256, 0, stream>>>(XK, WKT, bk, KS, nullptr, 4096, 1024, 1024, 1.0f);
    gemm_bt<1><<<dim3(8, 32), 256, 0, stream>>>(XV, WVT, bv, VT, nullptr, 4096, 1024, 1024, 1.0f);
    masknorm_kernel<<<4096, 256, 0, stream>>>(mask, FLAG, MBITS);
    attn_kernel<<<1024, 256, 0, stream>>>(QS, KS, VT, geom, MBITS, AO);
    gemm_bt<2><<<dim3(8, 32), 256, 0, stream>>>(AO, WOT, bo, Y, queries, 4096, 1024, 1024, 1.0f);
    ln_kernel<<<4096, 256, 0, stream>>>(Y, gamma, beta, (float*)d_out);
}